// Round 20
// baseline (1395.905 us; speedup 1.0000x reference)
//
#include <hip/hip_runtime.h>
#include <stdint.h>

#define NN 100000
#define NNP 100096          // NN padded to multiple of 128
#define NE 200000
#define NEP 200064          // NE padded to multiple of 128
#define NT 600000
#define HID 256

typedef __attribute__((ext_vector_type(8))) short bf16x8;
typedef __attribute__((ext_vector_type(4))) float f32x4;

__device__ __forceinline__ float bf2f(unsigned short u) {
    union { unsigned int i; float f; } x; x.i = ((unsigned int)u) << 16; return x.f;
}
__device__ __forceinline__ unsigned short f2bf(float f) {
    union { float f; unsigned int i; } x; x.f = f;
    unsigned int r = (x.i + 0x7FFFu + ((x.i >> 16) & 1u)) >> 16;
    return (unsigned short)r;
}

// async global->LDS, 16B per lane; LDS dest = wave-uniform base + lane*16
__device__ __forceinline__ void gload16(const void* g, void* l) {
    __builtin_amdgcn_global_load_lds(
        (const __attribute__((address_space(1))) void*)g,
        (__attribute__((address_space(3))) void*)l, 16, 0, 0);
}

// ---------------------------------------------------------------------------
// GEMM core, r20 variant: A staged via gload_lds+swizzle (proven), B read
// DIRECTLY from global — B (128-224 KB weights) is L2-resident on every XCD
// (FETCH 51.7MB proves single HBM fetch), so the LDS round-trip for it was
// pure overhead [catalog common-mistake #7 / m169]. LDS halves to 16 KB;
// each barrier drain now waits on 4 loads not 8.
// FAILED RESTRUCTURES (counter-evidenced): C^T epilogue swap (r12, -7%);
// multi-tile persistent loop (r14: acc spill); (256,5)/(512,6) bounds
// (r8/r10 spills); dbuf at 8 waves/CU (r5); 4-slot batch gathers (r18).
// Register budget: 512 wave-regs/SIMD unified VGPR+AGPR; 64 acc + ~60 addr
// = 124; (256,4) caps 128 — no slack.
// ---------------------------------------------------------------------------
template<int FLAGS, bool CBF>
__device__ __forceinline__
void gemm128_core(const unsigned short* __restrict__ A,
                  const unsigned short* __restrict__ BT,
                  const float* __restrict__ bias,
                  const unsigned short* __restrict__ res,
                  void* __restrict__ Cv, int row0, int col0,
                  int Mreal, int Kpad,
                  unsigned short* Asb)
{
    const int t    = threadIdx.x;
    const int lane = t & 63;
    const int wv   = t >> 6;          // 0..3
    const int wr   = wv >> 1;         // wave row half
    const int wc   = wv & 1;          // wave col half
    const int l15  = lane & 15;
    const int lk   = lane >> 4;
    const int sub  = lane >> 3;       // staging sub-row 0..7
    const int schk = lane & 7;        // staging 16B chunk 0..7

    f32x4 acc[4][4];
#pragma unroll
    for (int i = 0; i < 4; ++i)
#pragma unroll
        for (int j = 0; j < 4; ++j) acc[i][j] = (f32x4){0.f, 0.f, 0.f, 0.f};

    // B direct-from-global base: per-lane row (col0 + wc*64 + l15), k offset lk*8
    const unsigned short* Bw = BT + (size_t)(col0 + wc * 64 + l15) * Kpad + lk * 8;

    const int nt = Kpad >> 6;
    for (int kt = 0; kt < nt; ++kt) {
        const int k0 = kt << 6;
        // stage A tile 128x64 (16 segs of 8 rows; wave wv does segs wv*4+j)
#pragma unroll
        for (int j = 0; j < 4; ++j) {
            const int ii = wv * 4 + j;
            const int r  = ii * 8 + sub;
            const int cg = schk ^ (r & 7);
            gload16(A + (size_t)(row0 + r) * Kpad + k0 + cg * 8, Asb + ii * 512);
        }
        __syncthreads();     // drains A loads before reads
#pragma unroll
        for (int ks = 0; ks < 2; ++ks) {
            bf16x8 af[4], bfg[4];
#pragma unroll
            for (int mi = 0; mi < 4; ++mi) {
                const int r = wr * 64 + mi * 16 + l15;
                const int c = ks * 4 + lk;
                af[mi] = *(const bf16x8*)((const char*)Asb
                          + r * 128 + ((c ^ (r & 7)) << 4));
            }
#pragma unroll
            for (int ni = 0; ni < 4; ++ni)
                bfg[ni] = *(const bf16x8*)(Bw + (size_t)(ni * 16) * Kpad
                                           + k0 + ks * 32);
#pragma unroll
            for (int mi = 0; mi < 4; ++mi)
#pragma unroll
                for (int ni = 0; ni < 4; ++ni)
                    acc[mi][ni] = __builtin_amdgcn_mfma_f32_16x16x32_bf16(
                        af[mi], bfg[ni], acc[mi][ni], 0, 0, 0);
        }
        __syncthreads();     // A reads done before next stage overwrites
    }

    // epilogue: D col=l&15, row=(l>>4)*4+reg  [m89-verified]
#pragma unroll
    for (int mi = 0; mi < 4; ++mi) {
#pragma unroll
        for (int r = 0; r < 4; ++r) {
            const int row = row0 + wr * 64 + mi * 16 + lk * 4 + r;
            if (row >= Mreal) continue;
#pragma unroll
            for (int ni = 0; ni < 4; ++ni) {
                const int col = col0 + wc * 64 + ni * 16 + l15;
                float o = acc[mi][ni][r];
                if (FLAGS & 2) o += bias[col];
                if (FLAGS & 1) o = fmaxf(o, 0.f);
                if (FLAGS & 4) o += bf2f(res[(size_t)row * HID + col]);
                if (CBF) ((unsigned short*)Cv)[(size_t)row * HID + col] = f2bf(o);
                else     ((float*)Cv)[(size_t)row * HID + col] = o;
            }
        }
    }
}

// XCD-aware swizzle [T1]: x = xcd + 8*(member + MEMBERS*local_group).
template<int FLAGS, bool CBF>
__global__ __launch_bounds__(256, 4)
void gemm128(const unsigned short* __restrict__ A,
             const unsigned short* __restrict__ BT,
             const float* __restrict__ bias,
             const unsigned short* __restrict__ res,
             void* __restrict__ Cv, int Mtiles, int Mreal, int Kpad)
{
    __shared__ alignas(16) unsigned short Asb[128 * 64];
    const int x   = blockIdx.x;
    const int xcd = x & 7;
    const int ii  = x >> 3;
    const int g   = (ii >> 1) * 8 + xcd;     // tile-group = M tile
    const int ch  = ii & 1;
    if (g >= Mtiles) return;
    gemm128_core<FLAGS, CBF>(A, BT, bias, res, Cv, g * 128, ch * 128,
                             Mreal, Kpad, Asb);
}

// qkv: grid.x = Mtiles8 * 6; 6 members (3 proj x 2 halves) share one A tile
__global__ __launch_bounds__(256, 4)
void gemm128_qkv(const unsigned short* __restrict__ A,
                 const unsigned short* __restrict__ BTq,
                 const unsigned short* __restrict__ BTk,
                 const unsigned short* __restrict__ BTv,
                 unsigned short* __restrict__ Cq,
                 unsigned short* __restrict__ Ck,
                 unsigned short* __restrict__ Cvp, int Mtiles)
{
    __shared__ alignas(16) unsigned short Asb[128 * 64];
    const int x   = blockIdx.x;
    const int xcd = x & 7;
    const int ii  = x >> 3;
    const int g   = (ii / 6) * 8 + xcd;
    const int j   = ii % 6;
    if (g >= Mtiles) return;
    const int proj = j >> 1;
    const int ch   = j & 1;
    const unsigned short* BT = (proj == 0) ? BTq : (proj == 1) ? BTk : BTv;
    unsigned short*       C  = (proj == 0) ? Cq  : (proj == 1) ? Ck  : Cvp;
    gemm128_core<0, true>(A, BT, nullptr, nullptr, C, g * 128, ch * 128,
                          NE, 256, Asb);
}

// ---------------------------------------------------------------------------
// All 12 weight conversions in ONE launch. grid = (448, 12).
// ---------------------------------------------------------------------------
__global__ __launch_bounds__(256)
void wconv_all(const float* __restrict__ Wq, const float* __restrict__ Wk,
               const float* __restrict__ Wv, const float* __restrict__ L1w,
               const float* __restrict__ L2w, const float* __restrict__ W_i,
               const float* __restrict__ Wo,
               unsigned short* __restrict__ wT0,
               unsigned short* __restrict__ wiT,
               unsigned short* __restrict__ woT)
{
    const int y   = blockIdx.y;
    const int idx = blockIdx.x * 256 + threadIdx.x;
    if (y < 10) {
        if (idx >= 65536) return;
        const int l = y / 5, which = y - l * 5;
        const float* src;
        switch (which) {
            case 0: src = Wq;  break;
            case 1: src = Wk;  break;
            case 2: src = Wv;  break;
            case 3: src = L1w; break;
            default: src = L2w; break;
        }
        src += (size_t)l * 65536;
        const int n = idx >> 8, kp = idx & 255;
        wT0[(size_t)y * 65536 + idx] = f2bf(src[(size_t)kp * HID + n]);
    } else if (y == 10) {
        if (idx >= 256 * 192) return;
        const int n = idx / 192, kp = idx - n * 192;
        const float v = (kp < 147) ? W_i[(size_t)kp * HID + n] : 0.f;
        wiT[idx] = f2bf(v);
    } else {
        if (idx >= 256 * 448) return;
        const int n = idx / 448, kp = idx - n * 448;
        float v = 0.f;
        if (kp < 256)      v = Wo[(size_t)(133 + kp) * HID + n];
        else if (kp < 389) v = Wo[(size_t)(kp - 256) * HID + n];
        woT[idx] = f2bf(v);
    }
}

// ---------------------------------------------------------------------------
__global__ __launch_bounds__(256)
void build_initA(const float* __restrict__ atom, const float* __restrict__ edge,
                 const int* __restrict__ src, unsigned short* __restrict__ out)
{
    const int idx = blockIdx.x * 256 + threadIdx.x;
    const int e = idx / 24, j = idx - e * 24;
    if (e >= NE) return;
    const int c0 = j * 8;
    const int s  = src[e];
    bf16x8 o;
#pragma unroll
    for (int i = 0; i < 8; ++i) {
        const int c = c0 + i;
        float v = 0.f;
        if (c < 133)      v = atom[(size_t)s * 133 + c];
        else if (c < 147) v = edge[(size_t)e * 14 + (c - 133)];
        o[i] = (short)f2bf(v);
    }
    *(bf16x8*)(out + (size_t)e * 192 + c0) = o;
}

__global__ __launch_bounds__(256)
void build_final_atom(const float* __restrict__ atom, unsigned short* __restrict__ out)
{
    const int idx = blockIdx.x * 256 + threadIdx.x;
    const int n = idx / 24, j = idx - n * 24;
    if (n >= NNP) return;
    const int c0 = j * 8;
    bf16x8 o;
#pragma unroll
    for (int i = 0; i < 8; ++i) {
        const int c = c0 + i;
        float v = (n < NN && c < 133) ? atom[(size_t)n * 133 + c] : 0.f;
        o[i] = (short)f2bf(v);
    }
    *(bf16x8*)(out + (size_t)n * 448 + 256 + c0) = o;
}

// ---------------------------------------------------------------------------
// Combined CSR build
// ---------------------------------------------------------------------------
__global__ __launch_bounds__(256)
void count_both(const int* __restrict__ idx_ji, const int* __restrict__ dst,
                int* __restrict__ cnt)
{
    const int i = blockIdx.x * 256 + threadIdx.x;
    if (i < NT) {
        const int kk = idx_ji[i];
        if ((unsigned)kk < (unsigned)NE) atomicAdd(&cnt[kk], 1);
    } else {
        const int e = i - NT;
        if (e < NE) {
            const int kk = dst[e];
            if ((unsigned)kk < (unsigned)NN) atomicAdd(&cnt[NE + kk], 1);
        }
    }
}

__global__ __launch_bounds__(256)
void fill_both(const int* __restrict__ idx_ji, const int* __restrict__ idx_kj,
               const int* __restrict__ dst,
               int* __restrict__ cur, int* __restrict__ plist)
{
    const int i = blockIdx.x * 256 + threadIdx.x;
    if (i < NT) {
        const int kk = idx_ji[i];
        if ((unsigned)kk >= (unsigned)NE) return;
        const int pos = atomicAdd(&cur[kk], 1);
        if ((unsigned)pos < (unsigned)NT) plist[pos] = idx_kj[i];
    } else {
        const int e = i - NT;
        if (e >= NE) return;
        const int kk = dst[e];
        if ((unsigned)kk >= (unsigned)NN) return;
        const int pos = atomicAdd(&cur[NE + kk], 1);
        if ((unsigned)pos < (unsigned)(NT + NE)) plist[pos] = e;
    }
}

__global__ __launch_bounds__(256)
void scan1(const int* __restrict__ in, int n, int* __restrict__ excl,
           int* __restrict__ part)
{
    __shared__ int sh[256];
    const int t = threadIdx.x;
    const int base = blockIdx.x * 2048 + t * 8;
    int v[8]; int s = 0;
#pragma unroll
    for (int j = 0; j < 8; ++j) { v[j] = (base + j < n) ? in[base + j] : 0; s += v[j]; }
    sh[t] = s; __syncthreads();
    for (int off = 1; off < 256; off <<= 1) {
        int x = (t >= off) ? sh[t - off] : 0;
        __syncthreads();
        sh[t] += x;
        __syncthreads();
    }
    int ex = sh[t] - s;
#pragma unroll
    for (int j = 0; j < 8; ++j) { if (base + j < n) excl[base + j] = ex; ex += v[j]; }
    if (t == 255) part[blockIdx.x] = sh[255];
}

__global__ __launch_bounds__(256)
void scan2(int* __restrict__ part, int nparts)
{
    __shared__ int sh[256];
    const int t = threadIdx.x;
    const int v = (t < nparts) ? part[t] : 0;
    sh[t] = v; __syncthreads();
    for (int off = 1; off < 256; off <<= 1) {
        int x = (t >= off) ? sh[t - off] : 0;
        __syncthreads();
        sh[t] += x;
        __syncthreads();
    }
    if (t < nparts) part[t] = sh[t] - v;
}

__global__ __launch_bounds__(256)
void scan3(const int* __restrict__ excl, const int* __restrict__ part,
           const int* counts, int n, int* __restrict__ offs, int* cur)
{
    const int i = blockIdx.x * 256 + threadIdx.x;
    if (i >= n) return;
    const int v = excl[i] + part[i >> 11];
    const int c = counts[i];
    offs[i] = v;
    cur[i] = v;
    if (i == n - 1) offs[n] = v + c;
}

// ---------------------------------------------------------------------------
// Fused attention gather: 16 lanes per edge (4 edges/wave) + 1-deep q/v
// value prefetch (r17 proven form).
// ---------------------------------------------------------------------------
__global__ __launch_bounds__(256)
void gather_v(const unsigned short* __restrict__ q, const unsigned short* __restrict__ k,
              const unsigned short* __restrict__ v,
              const int* __restrict__ toff, const int* __restrict__ tkj,
              unsigned short* __restrict__ vc)
{
    const long gtid = (long)blockIdx.x * blockDim.x + threadIdx.x;
    const int w    = (int)(gtid >> 4);          // edge id
    const int lane = threadIdx.x & 15;          // 16 dims per lane
    if (w >= NE) return;
    int beg = toff[w], end = toff[w + 1];
    if (beg < 0) beg = 0;
    if (end > NT) end = NT;

    const size_t lo = (size_t)w * HID + lane * 16;
    const bf16x8 k0 = *(const bf16x8*)(k + lo);
    const bf16x8 k1 = *(const bf16x8*)(k + lo + 8);
    float kf[16];
#pragma unroll
    for (int j = 0; j < 8; ++j) { kf[j] = bf2f((unsigned short)k0[j]);
                                  kf[j + 8] = bf2f((unsigned short)k1[j]); }
    float av[16];
#pragma unroll
    for (int j = 0; j < 16; ++j) av[j] = 0.f;
    float den = 0.f;

    // prefetch slot
    bool okn = false; int an = 0;
    if (beg < end) {
        const int t0 = tkj[beg];
        okn = (unsigned)t0 < (unsigned)NE;
        an = okn ? t0 : 0;
    }
    bf16x8 qn0 = *(const bf16x8*)(q + (size_t)an * HID + lane * 16);
    bf16x8 qn1 = *(const bf16x8*)(q + (size_t)an * HID + lane * 16 + 8);
    bf16x8 vn0 = *(const bf16x8*)(v + (size_t)an * HID + lane * 16);
    bf16x8 vn1 = *(const bf16x8*)(v + (size_t)an * HID + lane * 16 + 8);

    for (int p = beg; p < end; ++p) {
        const bf16x8 q0 = qn0, q1 = qn1, v0 = vn0, v1 = vn1;
        const bool ok = okn;
        if (p + 1 < end) {
            const int tn = tkj[p + 1];
            okn = (unsigned)tn < (unsigned)NE;
            const int a2 = okn ? tn : 0;
            qn0 = *(const bf16x8*)(q + (size_t)a2 * HID + lane * 16);
            qn1 = *(const bf16x8*)(q + (size_t)a2 * HID + lane * 16 + 8);
            vn0 = *(const bf16x8*)(v + (size_t)a2 * HID + lane * 16);
            vn1 = *(const bf16x8*)(v + (size_t)a2 * HID + lane * 16 + 8);
        }
        if (!ok) continue;
        float s = 0.f;
#pragma unroll
        for (int j = 0; j < 8; ++j) {
            s += bf2f((unsigned short)q0[j]) * kf[j];
            s += bf2f((unsigned short)q1[j]) * kf[j + 8];
        }
        s += __shfl_xor(s, 1);                  // head = 2 lanes (d=32)
        const float lr = (s > 0.f) ? s : 0.2f * s;
        const float a  = __expf(lr);
        den += a;
#pragma unroll
        for (int j = 0; j < 8; ++j) {
            av[j]     += a * bf2f((unsigned short)v0[j]);
            av[j + 8] += a * bf2f((unsigned short)v1[j]);
        }
    }
    const float inv = (den != 0.f) ? 1.f / den : 0.f;
    bf16x8 o0, o1;
#pragma unroll
    for (int j = 0; j < 8; ++j) {
        o0[j] = (short)f2bf(av[j] * inv);
        o1[j] = (short)f2bf(av[j + 8] * inv);
    }
    *(bf16x8*)(vc + lo)     = o0;
    *(bf16x8*)(vc + lo + 8) = o1;
}

// ---------------------------------------------------------------------------
// edge->node gather: 16 lanes per node + value prefetch; writes bf16 directly
// into finalA cols [0,256) (row stride 448); pad rows get zeros.
// ---------------------------------------------------------------------------
__global__ __launch_bounds__(256)
void gather_node(const unsigned short* __restrict__ feats,
                 const int* __restrict__ noff, const int* __restrict__ nlist,
                 unsigned short* __restrict__ outA)
{
    const long gtid = (long)blockIdx.x * blockDim.x + threadIdx.x;
    const int w    = (int)(gtid >> 4);
    const int lane = threadIdx.x & 15;
    if (w >= NNP) return;
    unsigned short* out = outA + (size_t)w * 448 + lane * 16;
    if (w >= NN) {
        bf16x8 z = (bf16x8){0,0,0,0,0,0,0,0};
        *(bf16x8*)(out)     = z;
        *(bf16x8*)(out + 8) = z;
        return;
    }
    int beg = noff[w], end = noff[w + 1];
    if (beg < 0) beg = 0;
    if (end > NT + NE) end = NT + NE;

    float av[16];
#pragma unroll
    for (int j = 0; j < 16; ++j) av[j] = 0.f;

    bool okn = false; int an = 0;
    if (beg < end) {
        const int e0 = nlist[beg];
        okn = (unsigned)e0 < (unsigned)NE;
        an = okn ? e0 : 0;
    }
    bf16x8 fn0 = *(const bf16x8*)(feats + (size_t)an * HID + lane * 16);
    bf16x8 fn1 = *(const bf16x8*)(feats + (size_t)an * HID + lane * 16 + 8);

    for (int p = beg; p < end; ++p) {
        const bf16x8 f0 = fn0, f1 = fn1;
        const bool ok = okn;
        if (p + 1 < end) {
            const int en = nlist[p + 1];
            okn = (unsigned)en < (unsigned)NE;
            const int a2 = okn ? en : 0;
            fn0 = *(const bf16x8*)(feats + (size_t)a2 * HID + lane * 16);
            fn1 = *(const bf16x8*)(feats + (size_t)a2 * HID + lane * 16 + 8);
        }
        if (!ok) continue;
#pragma unroll
        for (int j = 0; j < 8; ++j) {
            av[j]     += bf2f((unsigned short)f0[j]);
            av[j + 8] += bf2f((unsigned short)f1[j]);
        }
    }
    bf16x8 o0, o1;
#pragma unroll
    for (int j = 0; j < 8; ++j) {
        o0[j] = (short)f2bf(av[j]);
        o1[j] = (short)f2bf(av[j + 8]);
    }
    *(bf16x8*)(out)     = o0;
    *(bf16x8*)(out + 8) = o1;
}

// ---------------------------------------------------------------------------
extern "C" void kernel_launch(void* const* d_in, const int* in_sizes, int n_in,
                              void* d_out, int out_size, void* d_ws, size_t ws_size,
                              hipStream_t stream)
{
    const float* atom = (const float*)d_in[0];
    const float* edge = (const float*)d_in[1];
    const float* W_i  = (const float*)d_in[2];
    const float* Wq   = (const float*)d_in[3];
    const float* Wk   = (const float*)d_in[4];
    const float* Wv   = (const float*)d_in[5];
    const float* L1w  = (const float*)d_in[6];
    const float* L1b  = (const float*)d_in[7];
    const float* L2w  = (const float*)d_in[8];
    const float* L2b  = (const float*)d_in[9];
    const float* Wo   = (const float*)d_in[10];
    const float* bo   = (const float*)d_in[11];
    const int* src    = (const int*)d_in[12];
    const int* dst    = (const int*)d_in[13];
    const int* idx_kj = (const int*)d_in[14];
    const int* idx_ji = (const int*)d_in[15];

    const size_t RB = (size_t)NE * HID * 2;   // 102,400,000 B
    char* ws = (char*)d_ws;
    unsigned short* feats = (unsigned short*)(ws);
    unsigned short* qb    = (unsigned short*)(ws + RB);
    unsigned short* kb    = (unsigned short*)(ws + 2 * RB);
    unsigned short* vb    = (unsigned short*)d_out;     // NE*256 bf16 == d_out bytes
    unsigned short* vc    = feats;                      // v_clone overlays feats
    unsigned short* initA = qb;                         // NEP*192 bf16 = 76.8MB < RB
    unsigned short* h1    = kb;
    unsigned short* finalA = kb;                        // NNP*448 bf16 = 89.7MB < RB

    const int NK = NE + NN;                 // combined key count
    char* p = ws + 3 * RB;
    int* offs     = (int*)p; p += ((size_t)NK + 16) * 4;
    int* cur      = (int*)p; p += ((size_t)NK + 16) * 4;
    int* plist    = (int*)p; p += (size_t)(NT + NE) * 4;
    int* tmp_excl = (int*)p; p += ((size_t)NK + 16) * 4;
    int* partials = (int*)p; p += 1024;
    unsigned short* wiT = (unsigned short*)p; p += (size_t)256 * 192 * 2;
    unsigned short* wT0 = (unsigned short*)p; p += (size_t)10 * 65536 * 2;
    unsigned short* woT = (unsigned short*)p; p += (size_t)256 * 448 * 2;
    const size_t NEEDED = (size_t)(p - ws);
    if (ws_size < NEEDED) return;
    auto wT = [&](int i) { return wT0 + (size_t)i * 65536; };

    const int MT_E  = NEP / 128;                 // 1563 M-tiles (edge GEMMs)
    const int MT_E8 = ((MT_E + 7) / 8) * 8;      // 1568
    const int MT_N  = NNP / 128;                 // 782 (final GEMM)
    const int MT_N8 = ((MT_N + 7) / 8) * 8;      // 784
    const int NPARTS = (NK + 2047) / 2048;       // 147 <= 256

    // ---- all weight conversions (one launch) ----
    wconv_all<<<dim3(448, 12), 256, 0, stream>>>(Wq, Wk, Wv, L1w, L2w, W_i, Wo,
                                                 wT0, wiT, woT);

    // ---- combined CSR build ----
    hipMemsetAsync(cur, 0, (size_t)NK * 4, stream);
    count_both<<<(NT + NE + 255) / 256, 256, 0, stream>>>(idx_ji, dst, cur);
    scan1<<<NPARTS, 256, 0, stream>>>(cur, NK, tmp_excl, partials);
    scan2<<<1, 256, 0, stream>>>(partials, NPARTS);
    scan3<<<(NK + 255) / 256, 256, 0, stream>>>(tmp_excl, partials, cur, NK, offs, cur);
    fill_both<<<(NT + NE + 255) / 256, 256, 0, stream>>>(idx_ji, idx_kj, dst, cur, plist);

    // ---- init: feats = relu(concat(atom[src], edge) @ W_i) ----
    build_initA<<<(NE * 24 + 255) / 256, 256, 0, stream>>>(atom, edge, src, initA);
    gemm128<1, true><<<MT_E8 * 2, 256, 0, stream>>>(initA, wiT, nullptr, nullptr,
                                                    feats, MT_E, NE, 192);

    // ---- 2 attention layers ----
    for (int l = 0; l < 2; ++l) {
        const float* l1b = L1b + (size_t)l * 256;
        const float* l2b = L2b + (size_t)l * 256;

        gemm128_qkv<<<MT_E8 * 6, 256, 0, stream>>>(
            feats, wT(l * 5 + 0), wT(l * 5 + 1), wT(l * 5 + 2), qb, kb, vb, MT_E);

        gather_v<<<(NE * 16) / 256, 256, 0, stream>>>(qb, kb, vb, offs, plist, vc);

        // h1 = relu(vc @ L1 + b1); feats = v + relu(h1 @ L2 + b2)
        gemm128<3, true><<<MT_E8 * 2, 256, 0, stream>>>(vc, wT(l * 5 + 3), l1b,
                                                        nullptr, h1, MT_E, NE, 256);
        gemm128<7, true><<<MT_E8 * 2, 256, 0, stream>>>(h1, wT(l * 5 + 4), l2b,
                                                        vb, feats, MT_E, NE, 256);
    }

    // ---- final projection: finalA = [fsum | atom | 0] (permuted K) ----
    gather_node<<<(NNP * 16 + 255) / 256, 256, 0, stream>>>(feats, offs + NE, plist, finalA);
    build_final_atom<<<(NNP * 24 + 255) / 256, 256, 0, stream>>>(atom, finalA);
    gemm128<3, false><<<MT_N8 * 2, 256, 0, stream>>>(finalA, woT, bo, nullptr,
                                                     d_out, MT_N, NN, 448);
}

// Round 21
// 1138.056 us; speedup vs baseline: 1.2266x; 1.2266x over previous
//
#include <hip/hip_runtime.h>
#include <stdint.h>

#define NN 100000
#define NNP 100096          // NN padded to multiple of 128
#define NE 200000
#define NEP 200064          // NE padded to multiple of 128
#define NT 600000
#define HID 256

typedef __attribute__((ext_vector_type(8))) short bf16x8;
typedef __attribute__((ext_vector_type(4))) float f32x4;

__device__ __forceinline__ float bf2f(unsigned short u) {
    union { unsigned int i; float f; } x; x.i = ((unsigned int)u) << 16; return x.f;
}
__device__ __forceinline__ unsigned short f2bf(float f) {
    union { float f; unsigned int i; } x; x.f = f;
    unsigned int r = (x.i + 0x7FFFu + ((x.i >> 16) & 1u)) >> 16;
    return (unsigned short)r;
}

// async global->LDS, 16B per lane; LDS dest = wave-uniform base + lane*16
__device__ __forceinline__ void gload16(const void* g, void* l) {
    __builtin_amdgcn_global_load_lds(
        (const __attribute__((address_space(1))) void*)g,
        (__attribute__((address_space(3))) void*)l, 16, 0, 0);
}

// ---------------------------------------------------------------------------
// m97-style GEMM core (round-13/17 proven form — FINAL).
// 4 waves (2x2), wave tile 64x64, BK=64, 32 KB LDS (A+B staged), 2-barrier
// loop, gload_lds staging, rule-21 swizzle pair.
// FULL REFUTED-LEVER LEDGER (all counter-evidenced):
//  r5  dbuf 64x256 @8 waves/CU: occupancy-starved (196 vs 151 us)
//  r8  bounds(256,5): acc spill (WRITE 300->536 MB)
//  r10 512thr/(512,6): acc spill (WRITE 1.7 GB, MfmaUtil 5%)
//  r12 C^T epilogue swap: -7% (stores weren't the bottleneck)
//  r14 multi-tile persistent: acc spill (live range across control flow)
//  r18 4-slot batch gathers: +23 us (wasted clamped-slot loads)
//  r20 B direct-from-L2: MFMA serialized on L2 latency (217 vs 151 us)
// Register budget: 512 wave-regs/SIMD unified VGPR+AGPR; 64 acc + ~60 addr
// = 124; (256,4) caps 128 — no slack for any extra control flow.
// ---------------------------------------------------------------------------
template<int FLAGS, bool CBF>
__device__ __forceinline__
void gemm128_core(const unsigned short* __restrict__ A,
                  const unsigned short* __restrict__ BT,
                  const float* __restrict__ bias,
                  const unsigned short* __restrict__ res,
                  void* __restrict__ Cv, int row0, int col0,
                  int Mreal, int Kpad,
                  unsigned short* Asb, unsigned short* Bsb)
{
    const int t    = threadIdx.x;
    const int lane = t & 63;
    const int wv   = t >> 6;          // 0..3
    const int wr   = wv >> 1;         // wave row half
    const int wc   = wv & 1;          // wave col half
    const int l15  = lane & 15;
    const int lk   = lane >> 4;
    const int sub  = lane >> 3;       // staging sub-row 0..7
    const int schk = lane & 7;        // staging 16B chunk 0..7

    f32x4 acc[4][4];
#pragma unroll
    for (int i = 0; i < 4; ++i)
#pragma unroll
        for (int j = 0; j < 4; ++j) acc[i][j] = (f32x4){0.f, 0.f, 0.f, 0.f};

    const int nt = Kpad >> 6;
    for (int kt = 0; kt < nt; ++kt) {
        const int k0 = kt << 6;
#pragma unroll
        for (int j = 0; j < 4; ++j) {
            const int ii = wv * 4 + j;
            const int r  = ii * 8 + sub;
            const int cg = schk ^ (r & 7);
            gload16(A + (size_t)(row0 + r) * Kpad + k0 + cg * 8, Asb + ii * 512);
        }
#pragma unroll
        for (int j = 0; j < 4; ++j) {
            const int ii = wv * 4 + j;
            const int r  = ii * 8 + sub;
            const int cg = schk ^ (r & 7);
            gload16(BT + (size_t)(col0 + r) * Kpad + k0 + cg * 8, Bsb + ii * 512);
        }
        __syncthreads();     // compiler drains vmcnt before s_barrier
#pragma unroll
        for (int ks = 0; ks < 2; ++ks) {
            bf16x8 af[4], bfg[4];
#pragma unroll
            for (int mi = 0; mi < 4; ++mi) {
                const int r = wr * 64 + mi * 16 + l15;
                const int c = ks * 4 + lk;
                af[mi] = *(const bf16x8*)((const char*)Asb
                          + r * 128 + ((c ^ (r & 7)) << 4));
            }
#pragma unroll
            for (int ni = 0; ni < 4; ++ni) {
                const int r = wc * 64 + ni * 16 + l15;
                const int c = ks * 4 + lk;
                bfg[ni] = *(const bf16x8*)((const char*)Bsb
                           + r * 128 + ((c ^ (r & 7)) << 4));
            }
#pragma unroll
            for (int mi = 0; mi < 4; ++mi)
#pragma unroll
                for (int ni = 0; ni < 4; ++ni)
                    acc[mi][ni] = __builtin_amdgcn_mfma_f32_16x16x32_bf16(
                        af[mi], bfg[ni], acc[mi][ni], 0, 0, 0);
        }
        __syncthreads();     // reads done before next stage overwrites
    }

    // epilogue: D col=l&15, row=(l>>4)*4+reg  [m89-verified]
#pragma unroll
    for (int mi = 0; mi < 4; ++mi) {
#pragma unroll
        for (int r = 0; r < 4; ++r) {
            const int row = row0 + wr * 64 + mi * 16 + lk * 4 + r;
            if (row >= Mreal) continue;
#pragma unroll
            for (int ni = 0; ni < 4; ++ni) {
                const int col = col0 + wc * 64 + ni * 16 + l15;
                float o = acc[mi][ni][r];
                if (FLAGS & 2) o += bias[col];
                if (FLAGS & 1) o = fmaxf(o, 0.f);
                if (FLAGS & 4) o += bf2f(res[(size_t)row * HID + col]);
                if (CBF) ((unsigned short*)Cv)[(size_t)row * HID + col] = f2bf(o);
                else     ((float*)Cv)[(size_t)row * HID + col] = o;
            }
        }
    }
}

// XCD-aware swizzle [T1]: x = xcd + 8*(member + MEMBERS*local_group).
template<int FLAGS, bool CBF>
__global__ __launch_bounds__(256, 4)
void gemm128(const unsigned short* __restrict__ A,
             const unsigned short* __restrict__ BT,
             const float* __restrict__ bias,
             const unsigned short* __restrict__ res,
             void* __restrict__ Cv, int Mtiles, int Mreal, int Kpad)
{
    __shared__ alignas(16) unsigned short Asb[128 * 64];
    __shared__ alignas(16) unsigned short Bsb[128 * 64];
    const int x   = blockIdx.x;
    const int xcd = x & 7;
    const int ii  = x >> 3;
    const int g   = (ii >> 1) * 8 + xcd;     // tile-group = M tile
    const int ch  = ii & 1;
    if (g >= Mtiles) return;
    gemm128_core<FLAGS, CBF>(A, BT, bias, res, Cv, g * 128, ch * 128,
                             Mreal, Kpad, Asb, Bsb);
}

// qkv: grid.x = Mtiles8 * 6; 6 members (3 proj x 2 halves) share one A tile
__global__ __launch_bounds__(256, 4)
void gemm128_qkv(const unsigned short* __restrict__ A,
                 const unsigned short* __restrict__ BTq,
                 const unsigned short* __restrict__ BTk,
                 const unsigned short* __restrict__ BTv,
                 unsigned short* __restrict__ Cq,
                 unsigned short* __restrict__ Ck,
                 unsigned short* __restrict__ Cvp, int Mtiles)
{
    __shared__ alignas(16) unsigned short Asb[128 * 64];
    __shared__ alignas(16) unsigned short Bsb[128 * 64];
    const int x   = blockIdx.x;
    const int xcd = x & 7;
    const int ii  = x >> 3;
    const int g   = (ii / 6) * 8 + xcd;
    const int j   = ii % 6;
    if (g >= Mtiles) return;
    const int proj = j >> 1;
    const int ch   = j & 1;
    const unsigned short* BT = (proj == 0) ? BTq : (proj == 1) ? BTk : BTv;
    unsigned short*       C  = (proj == 0) ? Cq  : (proj == 1) ? Ck  : Cvp;
    gemm128_core<0, true>(A, BT, nullptr, nullptr, C, g * 128, ch * 128,
                          NE, 256, Asb, Bsb);
}

// ---------------------------------------------------------------------------
// All 12 weight conversions in ONE launch. grid = (448, 12).
// ---------------------------------------------------------------------------
__global__ __launch_bounds__(256)
void wconv_all(const float* __restrict__ Wq, const float* __restrict__ Wk,
               const float* __restrict__ Wv, const float* __restrict__ L1w,
               const float* __restrict__ L2w, const float* __restrict__ W_i,
               const float* __restrict__ Wo,
               unsigned short* __restrict__ wT0,
               unsigned short* __restrict__ wiT,
               unsigned short* __restrict__ woT)
{
    const int y   = blockIdx.y;
    const int idx = blockIdx.x * 256 + threadIdx.x;
    if (y < 10) {
        if (idx >= 65536) return;
        const int l = y / 5, which = y - l * 5;
        const float* src;
        switch (which) {
            case 0: src = Wq;  break;
            case 1: src = Wk;  break;
            case 2: src = Wv;  break;
            case 3: src = L1w; break;
            default: src = L2w; break;
        }
        src += (size_t)l * 65536;
        const int n = idx >> 8, kp = idx & 255;
        wT0[(size_t)y * 65536 + idx] = f2bf(src[(size_t)kp * HID + n]);
    } else if (y == 10) {
        if (idx >= 256 * 192) return;
        const int n = idx / 192, kp = idx - n * 192;
        const float v = (kp < 147) ? W_i[(size_t)kp * HID + n] : 0.f;
        wiT[idx] = f2bf(v);
    } else {
        if (idx >= 256 * 448) return;
        const int n = idx / 448, kp = idx - n * 448;
        float v = 0.f;
        if (kp < 256)      v = Wo[(size_t)(133 + kp) * HID + n];
        else if (kp < 389) v = Wo[(size_t)(kp - 256) * HID + n];
        woT[idx] = f2bf(v);
    }
}

// ---------------------------------------------------------------------------
__global__ __launch_bounds__(256)
void build_initA(const float* __restrict__ atom, const float* __restrict__ edge,
                 const int* __restrict__ src, unsigned short* __restrict__ out)
{
    const int idx = blockIdx.x * 256 + threadIdx.x;
    const int e = idx / 24, j = idx - e * 24;
    if (e >= NE) return;
    const int c0 = j * 8;
    const int s  = src[e];
    bf16x8 o;
#pragma unroll
    for (int i = 0; i < 8; ++i) {
        const int c = c0 + i;
        float v = 0.f;
        if (c < 133)      v = atom[(size_t)s * 133 + c];
        else if (c < 147) v = edge[(size_t)e * 14 + (c - 133)];
        o[i] = (short)f2bf(v);
    }
    *(bf16x8*)(out + (size_t)e * 192 + c0) = o;
}

__global__ __launch_bounds__(256)
void build_final_atom(const float* __restrict__ atom, unsigned short* __restrict__ out)
{
    const int idx = blockIdx.x * 256 + threadIdx.x;
    const int n = idx / 24, j = idx - n * 24;
    if (n >= NNP) return;
    const int c0 = j * 8;
    bf16x8 o;
#pragma unroll
    for (int i = 0; i < 8; ++i) {
        const int c = c0 + i;
        float v = (n < NN && c < 133) ? atom[(size_t)n * 133 + c] : 0.f;
        o[i] = (short)f2bf(v);
    }
    *(bf16x8*)(out + (size_t)n * 448 + 256 + c0) = o;
}

// ---------------------------------------------------------------------------
// Combined CSR build
// ---------------------------------------------------------------------------
__global__ __launch_bounds__(256)
void count_both(const int* __restrict__ idx_ji, const int* __restrict__ dst,
                int* __restrict__ cnt)
{
    const int i = blockIdx.x * 256 + threadIdx.x;
    if (i < NT) {
        const int kk = idx_ji[i];
        if ((unsigned)kk < (unsigned)NE) atomicAdd(&cnt[kk], 1);
    } else {
        const int e = i - NT;
        if (e < NE) {
            const int kk = dst[e];
            if ((unsigned)kk < (unsigned)NN) atomicAdd(&cnt[NE + kk], 1);
        }
    }
}

__global__ __launch_bounds__(256)
void fill_both(const int* __restrict__ idx_ji, const int* __restrict__ idx_kj,
               const int* __restrict__ dst,
               int* __restrict__ cur, int* __restrict__ plist)
{
    const int i = blockIdx.x * 256 + threadIdx.x;
    if (i < NT) {
        const int kk = idx_ji[i];
        if ((unsigned)kk >= (unsigned)NE) return;
        const int pos = atomicAdd(&cur[kk], 1);
        if ((unsigned)pos < (unsigned)NT) plist[pos] = idx_kj[i];
    } else {
        const int e = i - NT;
        if (e >= NE) return;
        const int kk = dst[e];
        if ((unsigned)kk >= (unsigned)NN) return;
        const int pos = atomicAdd(&cur[NE + kk], 1);
        if ((unsigned)pos < (unsigned)(NT + NE)) plist[pos] = e;
    }
}

__global__ __launch_bounds__(256)
void scan1(const int* __restrict__ in, int n, int* __restrict__ excl,
           int* __restrict__ part)
{
    __shared__ int sh[256];
    const int t = threadIdx.x;
    const int base = blockIdx.x * 2048 + t * 8;
    int v[8]; int s = 0;
#pragma unroll
    for (int j = 0; j < 8; ++j) { v[j] = (base + j < n) ? in[base + j] : 0; s += v[j]; }
    sh[t] = s; __syncthreads();
    for (int off = 1; off < 256; off <<= 1) {
        int x = (t >= off) ? sh[t - off] : 0;
        __syncthreads();
        sh[t] += x;
        __syncthreads();
    }
    int ex = sh[t] - s;
#pragma unroll
    for (int j = 0; j < 8; ++j) { if (base + j < n) excl[base + j] = ex; ex += v[j]; }
    if (t == 255) part[blockIdx.x] = sh[255];
}

__global__ __launch_bounds__(256)
void scan2(int* __restrict__ part, int nparts)
{
    __shared__ int sh[256];
    const int t = threadIdx.x;
    const int v = (t < nparts) ? part[t] : 0;
    sh[t] = v; __syncthreads();
    for (int off = 1; off < 256; off <<= 1) {
        int x = (t >= off) ? sh[t - off] : 0;
        __syncthreads();
        sh[t] += x;
        __syncthreads();
    }
    if (t < nparts) part[t] = sh[t] - v;
}

__global__ __launch_bounds__(256)
void scan3(const int* __restrict__ excl, const int* __restrict__ part,
           const int* counts, int n, int* __restrict__ offs, int* cur)
{
    const int i = blockIdx.x * 256 + threadIdx.x;
    if (i >= n) return;
    const int v = excl[i] + part[i >> 11];
    const int c = counts[i];
    offs[i] = v;
    cur[i] = v;
    if (i == n - 1) offs[n] = v + c;
}

// ---------------------------------------------------------------------------
// Fused attention gather: 16 lanes per edge (4 edges/wave) + 1-deep q/v
// value prefetch (r17 proven form).
// ---------------------------------------------------------------------------
__global__ __launch_bounds__(256)
void gather_v(const unsigned short* __restrict__ q, const unsigned short* __restrict__ k,
              const unsigned short* __restrict__ v,
              const int* __restrict__ toff, const int* __restrict__ tkj,
              unsigned short* __restrict__ vc)
{
    const long gtid = (long)blockIdx.x * blockDim.x + threadIdx.x;
    const int w    = (int)(gtid >> 4);          // edge id
    const int lane = threadIdx.x & 15;          // 16 dims per lane
    if (w >= NE) return;
    int beg = toff[w], end = toff[w + 1];
    if (beg < 0) beg = 0;
    if (end > NT) end = NT;

    const size_t lo = (size_t)w * HID + lane * 16;
    const bf16x8 k0 = *(const bf16x8*)(k + lo);
    const bf16x8 k1 = *(const bf16x8*)(k + lo + 8);
    float kf[16];
#pragma unroll
    for (int j = 0; j < 8; ++j) { kf[j] = bf2f((unsigned short)k0[j]);
                                  kf[j + 8] = bf2f((unsigned short)k1[j]); }
    float av[16];
#pragma unroll
    for (int j = 0; j < 16; ++j) av[j] = 0.f;
    float den = 0.f;

    // prefetch slot
    bool okn = false; int an = 0;
    if (beg < end) {
        const int t0 = tkj[beg];
        okn = (unsigned)t0 < (unsigned)NE;
        an = okn ? t0 : 0;
    }
    bf16x8 qn0 = *(const bf16x8*)(q + (size_t)an * HID + lane * 16);
    bf16x8 qn1 = *(const bf16x8*)(q + (size_t)an * HID + lane * 16 + 8);
    bf16x8 vn0 = *(const bf16x8*)(v + (size_t)an * HID + lane * 16);
    bf16x8 vn1 = *(const bf16x8*)(v + (size_t)an * HID + lane * 16 + 8);

    for (int p = beg; p < end; ++p) {
        const bf16x8 q0 = qn0, q1 = qn1, v0 = vn0, v1 = vn1;
        const bool ok = okn;
        if (p + 1 < end) {
            const int tn = tkj[p + 1];
            okn = (unsigned)tn < (unsigned)NE;
            const int a2 = okn ? tn : 0;
            qn0 = *(const bf16x8*)(q + (size_t)a2 * HID + lane * 16);
            qn1 = *(const bf16x8*)(q + (size_t)a2 * HID + lane * 16 + 8);
            vn0 = *(const bf16x8*)(v + (size_t)a2 * HID + lane * 16);
            vn1 = *(const bf16x8*)(v + (size_t)a2 * HID + lane * 16 + 8);
        }
        if (!ok) continue;
        float s = 0.f;
#pragma unroll
        for (int j = 0; j < 8; ++j) {
            s += bf2f((unsigned short)q0[j]) * kf[j];
            s += bf2f((unsigned short)q1[j]) * kf[j + 8];
        }
        s += __shfl_xor(s, 1);                  // head = 2 lanes (d=32)
        const float lr = (s > 0.f) ? s : 0.2f * s;
        const float a  = __expf(lr);
        den += a;
#pragma unroll
        for (int j = 0; j < 8; ++j) {
            av[j]     += a * bf2f((unsigned short)v0[j]);
            av[j + 8] += a * bf2f((unsigned short)v1[j]);
        }
    }
    const float inv = (den != 0.f) ? 1.f / den : 0.f;
    bf16x8 o0, o1;
#pragma unroll
    for (int j = 0; j < 8; ++j) {
        o0[j] = (short)f2bf(av[j] * inv);
        o1[j] = (short)f2bf(av[j + 8] * inv);
    }
    *(bf16x8*)(vc + lo)     = o0;
    *(bf16x8*)(vc + lo + 8) = o1;
}

// ---------------------------------------------------------------------------
// edge->node gather: 16 lanes per node + value prefetch; writes bf16 directly
// into finalA cols [0,256) (row stride 448); pad rows get zeros.
// ---------------------------------------------------------------------------
__global__ __launch_bounds__(256)
void gather_node(const unsigned short* __restrict__ feats,
                 const int* __restrict__ noff, const int* __restrict__ nlist,
                 unsigned short* __restrict__ outA)
{
    const long gtid = (long)blockIdx.x * blockDim.x + threadIdx.x;
    const int w    = (int)(gtid >> 4);
    const int lane = threadIdx.x & 15;
    if (w >= NNP) return;
    unsigned short* out = outA + (size_t)w * 448 + lane * 16;
    if (w >= NN) {
        bf16x8 z = (bf16x8){0,0,0,0,0,0,0,0};
        *(bf16x8*)(out)     = z;
        *(bf16x8*)(out + 8) = z;
        return;
    }
    int beg = noff[w], end = noff[w + 1];
    if (beg < 0) beg = 0;
    if (end > NT + NE) end = NT + NE;

    float av[16];
#pragma unroll
    for (int j = 0; j < 16; ++j) av[j] = 0.f;

    bool okn = false; int an = 0;
    if (beg < end) {
        const int e0 = nlist[beg];
        okn = (unsigned)e0 < (unsigned)NE;
        an = okn ? e0 : 0;
    }
    bf16x8 fn0 = *(const bf16x8*)(feats + (size_t)an * HID + lane * 16);
    bf16x8 fn1 = *(const bf16x8*)(feats + (size_t)an * HID + lane * 16 + 8);

    for (int p = beg; p < end; ++p) {
        const bf16x8 f0 = fn0, f1 = fn1;
        const bool ok = okn;
        if (p + 1 < end) {
            const int en = nlist[p + 1];
            okn = (unsigned)en < (unsigned)NE;
            const int a2 = okn ? en : 0;
            fn0 = *(const bf16x8*)(feats + (size_t)a2 * HID + lane * 16);
            fn1 = *(const bf16x8*)(feats + (size_t)a2 * HID + lane * 16 + 8);
        }
        if (!ok) continue;
#pragma unroll
        for (int j = 0; j < 8; ++j) {
            av[j]     += bf2f((unsigned short)f0[j]);
            av[j + 8] += bf2f((unsigned short)f1[j]);
        }
    }
    bf16x8 o0, o1;
#pragma unroll
    for (int j = 0; j < 8; ++j) {
        o0[j] = (short)f2bf(av[j]);
        o1[j] = (short)f2bf(av[j + 8]);
    }
    *(bf16x8*)(out)     = o0;
    *(bf16x8*)(out + 8) = o1;
}

// ---------------------------------------------------------------------------
extern "C" void kernel_launch(void* const* d_in, const int* in_sizes, int n_in,
                              void* d_out, int out_size, void* d_ws, size_t ws_size,
                              hipStream_t stream)
{
    const float* atom = (const float*)d_in[0];
    const float* edge = (const float*)d_in[1];
    const float* W_i  = (const float*)d_in[2];
    const float* Wq   = (const float*)d_in[3];
    const float* Wk   = (const float*)d_in[4];
    const float* Wv   = (const float*)d_in[5];
    const float* L1w  = (const float*)d_in[6];
    const float* L1b  = (const float*)d_in[7];
    const float* L2w  = (const float*)d_in[8];
    const float* L2b  = (const float*)d_in[9];
    const float* Wo   = (const float*)d_in[10];
    const float* bo   = (const float*)d_in[11];
    const int* src    = (const int*)d_in[12];
    const int* dst    = (const int*)d_in[13];
    const int* idx_kj = (const int*)d_in[14];
    const int* idx_ji = (const int*)d_in[15];

    const size_t RB = (size_t)NE * HID * 2;   // 102,400,000 B
    char* ws = (char*)d_ws;
    unsigned short* feats = (unsigned short*)(ws);
    unsigned short* qb    = (unsigned short*)(ws + RB);
    unsigned short* kb    = (unsigned short*)(ws + 2 * RB);
    unsigned short* vb    = (unsigned short*)d_out;     // NE*256 bf16 == d_out bytes
    unsigned short* vc    = feats;                      // v_clone overlays feats
    unsigned short* initA = qb;                         // NEP*192 bf16 = 76.8MB < RB
    unsigned short* h1    = kb;
    unsigned short* finalA = kb;                        // NNP*448 bf16 = 89.7MB < RB

    const int NK = NE + NN;                 // combined key count
    char* p = ws + 3 * RB;
    int* offs     = (int*)p; p += ((size_t)NK + 16) * 4;
    int* cur      = (int*)p; p += ((size_t)NK + 16) * 4;
    int* plist    = (int*)p; p += (size_t)(NT + NE) * 4;
    int* tmp_excl = (int*)p; p += ((size_t)NK + 16) * 4;
    int* partials = (int*)p; p += 1024;
    unsigned short* wiT = (unsigned short*)p; p += (size_t)256 * 192 * 2;
    unsigned short* wT0 = (unsigned short*)p; p += (size_t)10 * 65536 * 2;
    unsigned short* woT = (unsigned short*)p; p += (size_t)256 * 448 * 2;
    const size_t NEEDED = (size_t)(p - ws);
    if (ws_size < NEEDED) return;
    auto wT = [&](int i) { return wT0 + (size_t)i * 65536; };

    const int MT_E  = NEP / 128;                 // 1563 M-tiles (edge GEMMs)
    const int MT_E8 = ((MT_E + 7) / 8) * 8;      // 1568
    const int MT_N  = NNP / 128;                 // 782 (final GEMM)
    const int MT_N8 = ((MT_N + 7) / 8) * 8;      // 784
    const int NPARTS = (NK + 2047) / 2048;       // 147 <= 256

    // ---- all weight conversions (one launch) ----
    wconv_all<<<dim3(448, 12), 256, 0, stream>>>(Wq, Wk, Wv, L1w, L2w, W_i, Wo,
                                                 wT0, wiT, woT);

    // ---- combined CSR build ----
    hipMemsetAsync(cur, 0, (size_t)NK * 4, stream);
    count_both<<<(NT + NE + 255) / 256, 256, 0, stream>>>(idx_ji, dst, cur);
    scan1<<<NPARTS, 256, 0, stream>>>(cur, NK, tmp_excl, partials);
    scan2<<<1, 256, 0, stream>>>(partials, NPARTS);
    scan3<<<(NK + 255) / 256, 256, 0, stream>>>(tmp_excl, partials, cur, NK, offs, cur);
    fill_both<<<(NT + NE + 255) / 256, 256, 0, stream>>>(idx_ji, idx_kj, dst, cur, plist);

    // ---- init: feats = relu(concat(atom[src], edge) @ W_i) ----
    build_initA<<<(NE * 24 + 255) / 256, 256, 0, stream>>>(atom, edge, src, initA);
    gemm128<1, true><<<MT_E8 * 2, 256, 0, stream>>>(initA, wiT, nullptr, nullptr,
                                                    feats, MT_E, NE, 192);

    // ---- 2 attention layers ----
    for (int l = 0; l < 2; ++l) {
        const float* l1b = L1b + (size_t)l * 256;
        const float* l2b = L2b + (size_t)l * 256;

        gemm128_qkv<<<MT_E8 * 6, 256, 0, stream>>>(
            feats, wT(l * 5 + 0), wT(l * 5 + 1), wT(l * 5 + 2), qb, kb, vb, MT_E);

        gather_v<<<(NE * 16) / 256, 256, 0, stream>>>(qb, kb, vb, offs, plist, vc);

        // h1 = relu(vc @ L1 + b1); feats = v + relu(h1 @ L2 + b2)
        gemm128<3, true><<<MT_E8 * 2, 256, 0, stream>>>(vc, wT(l * 5 + 3), l1b,
                                                        nullptr, h1, MT_E, NE, 256);
        gemm128<7, true><<<MT_E8 * 2, 256, 0, stream>>>(h1, wT(l * 5 + 4), l2b,
                                                        vb, feats, MT_E, NE, 256);
    }

    // ---- final projection: finalA = [fsum | atom | 0] (permuted K) ----
    gather_node<<<(NNP * 16 + 255) / 256, 256, 0, stream>>>(feats, offs + NE, plist, finalA);
    build_final_atom<<<(NNP * 24 + 255) / 256, 256, 0, stream>>>(atom, finalA);
    gemm128<3, false><<<MT_N8 * 2, 256, 0, stream>>>(finalA, woT, bo, nullptr,
                                                     d_out, MT_N, NN, 448);
}